// Round 16
// baseline (583.456 us; speedup 1.0000x reference)
//
#include <hip/hip_runtime.h>
#include <hip/hip_bf16.h>
#include <stdint.h>

#define N_ENC 2048
#define BATCH 32
#define M_TOT (N_ENC * BATCH)   // 65536 rows (s*32+b)
#define K_DIM 1024
#define N_DIM 1024
#define BK 64
#define NT (K_DIM / BK)          // 16 K-tiles
#define NSLAB 16                 // nt8*2 + wn (race-free logit partials)

typedef __attribute__((ext_vector_type(4))) float f32x4;
typedef __attribute__((ext_vector_type(8))) short short8;

__device__ __forceinline__ unsigned int pack_bf16x2(float lo, float hi) {
  unsigned int a = __float_as_uint(lo);
  unsigned int b = __float_as_uint(hi);
  a = (a + 0x7fffu + ((a >> 16) & 1u)) >> 16;          // RNE to bf16, low half
  b = (b + 0x7fffu + ((b >> 16) & 1u)) & 0xffff0000u;  // RNE to bf16, high half
  return a | b;
}

__device__ __forceinline__ float bf2f(unsigned short u) {
  return __uint_as_float((unsigned int)u << 16);
}

__device__ __forceinline__ float tanh_fast(float x) {
  float e = __expf(2.0f * x);
  return 1.0f - 2.0f / (e + 1.0f);
}

__device__ __forceinline__ int mask_mode_detect(const void* maskp, int t,
                                                int* mf) {
  if (t < 2) mf[t] = 0;
  __syncthreads();
  unsigned w0 = ((const unsigned*)maskp)[t & 255];
  if (t < 256) {
    if (w0 == 0x3f800000u) mf[1] = 1;
    else if (w0 > 1u) mf[0] = 1;
  }
  __syncthreads();
  return mf[1] ? 2 : (mf[0] ? 1 : 0);
}

__device__ __forceinline__ int mask_read(const void* maskp, int mode, int idx) {
  if (mode == 0) return ((const int*)maskp)[idx] != 0;
  if (mode == 1) return ((const unsigned char*)maskp)[idx] != 0;
  return ((const float*)maskp)[idx] != 0.f;
}

// ---- phase 1: per-block (256 rows) mask counts ----
__global__ __launch_bounds__(256) void k_count(const void* __restrict__ maskp,
                                               int* __restrict__ bcnt) {
  const int t = threadIdx.x, lane = t & 63, wv = t >> 6;
  __shared__ int mf[2];
  __shared__ int ws_[4];
  const int mode = mask_mode_detect(maskp, t, mf);
  const int idx = blockIdx.x * 256 + t;
  int mk = mask_read(maskp, mode, idx);
  unsigned long long bal = __ballot(mk);
  if (lane == 0) ws_[wv] = __popcll(bal);
  __syncthreads();
  if (t == 0) bcnt[blockIdx.x] = ws_[0] + ws_[1] + ws_[2] + ws_[3];
}

// ---- phase 2: pos/ridx fill via block-prefix + in-block ballot compaction ----
__global__ __launch_bounds__(256) void k_fill(const void* __restrict__ maskp,
                                              const int* __restrict__ bcnt,
                                              int* __restrict__ pos,
                                              int* __restrict__ ridx,
                                              int* __restrict__ mcount) {
  const int t = threadIdx.x, lane = t & 63, wv = t >> 6;
  __shared__ int mf[2];
  __shared__ int sc[256];
  __shared__ int wtot[4];
  __shared__ int wcnt[4];
  const int mode = mask_mode_detect(maskp, t, mf);

  int x = bcnt[t];
#pragma unroll
  for (int d = 1; d < 64; d <<= 1) {
    int y = __shfl_up(x, d);
    if (lane >= d) x += y;
  }
  if (lane == 63) wtot[wv] = x;
  __syncthreads();
  int add = 0;
  for (int i = 0; i < wv; ++i) add += wtot[i];
  sc[t] = x + add;
  __syncthreads();
  const int blockoff = blockIdx.x ? sc[blockIdx.x - 1] : 0;
  if (blockIdx.x == 0 && t == 0) *mcount = sc[255];

  const int idx = blockIdx.x * 256 + t;
  int mk = mask_read(maskp, mode, idx);
  unsigned long long bal = __ballot(mk);
  int lpfx = __popcll(bal & ((1ULL << lane) - 1ULL));
  if (lane == 0) wcnt[wv] = __popcll(bal);
  __syncthreads();
  int wb = 0;
  for (int i = 0; i < wv; ++i) wb += wcnt[i];
  int off = blockoff + wb + lpfx;
  if (mk) { pos[idx] = off; ridx[off] = idx; }
  else pos[idx] = -1;
}

// ---- gather + f32->bf16: cmp[j] = bf16(enc[ridx[j]]), j < mcount ----
__global__ void k_gather_cvt(const float* __restrict__ enc,
                             const int* __restrict__ ridx,
                             const int* __restrict__ mcount,
                             unsigned short* __restrict__ cmp) {
  const int mc = *mcount;
  const int e = threadIdx.x * 4;
  for (int j = blockIdx.x; j < mc; j += gridDim.x) {
    const int row = ridx[j];
    f32x4 v = *(const f32x4*)(enc + (size_t)row * K_DIM + e);
    uint2 o;
    o.x = pack_bf16x2(v.x, v.y);
    o.y = pack_bf16x2(v.z, v.w);
    *(uint2*)(cmp + (size_t)j * K_DIM + e) = o;
  }
}

// ---- w_enc f32 -> bf16 ----
__global__ void k_convert_bf16(const float* __restrict__ src,
                               unsigned short* __restrict__ dst, int n8) {
  for (int i = blockIdx.x * 256 + threadIdx.x; i < n8; i += gridDim.x * 256) {
    const float* p = src + (size_t)i * 8;
    f32x4 v0 = *(const f32x4*)p;
    f32x4 v1 = *(const f32x4*)(p + 4);
    uint4 o;
    o.x = pack_bf16x2(v0.x, v0.y);
    o.y = pack_bf16x2(v0.z, v0.w);
    o.z = pack_bf16x2(v1.x, v1.y);
    o.w = pack_bf16x2(v1.z, v1.w);
    *(uint4*)(dst + (size_t)i * 8) = o;
  }
}

// ---- proj_dec[b][h] = sum_d dec[b][d] * w_dec[h][d] ----
__global__ void k_proj_dec(const float* __restrict__ dec,
                           const float* __restrict__ w_dec,
                           float* __restrict__ proj) {
  int t = threadIdx.x;
  int hh = t & 7, b = t >> 3;
  int h = blockIdx.x * 8 + hh;
  const float* wr = w_dec + (size_t)h * K_DIM;
  const float* dr = dec + (size_t)b * K_DIM;
  float acc = 0.f;
  for (int d = 0; d < K_DIM; d += 4) {
    f32x4 wv = *(const f32x4*)(wr + d);
    f32x4 dv = *(const f32x4*)(dr + d);
    acc = fmaf(wv.x, dv.x, acc);
    acc = fmaf(wv.y, dv.y, acc);
    acc = fmaf(wv.z, dv.z, acc);
    acc = fmaf(wv.w, dv.w, acc);
  }
  proj[b * N_DIM + h] = acc;
}

// ---- R9 GEMM on compacted rows; compaction-aware XCD swizzle ----
__global__ __launch_bounds__(256, 3) void k_gemm128(
    const unsigned short* __restrict__ Abf,  // cmp bf16
    const unsigned short* __restrict__ B,    // w_enc bf16 [1024][1024]
    const int* __restrict__ ridx,
    const int* __restrict__ mcount,
    const float* __restrict__ pdec,          // [32][1024]
    const float* __restrict__ wout,          // [1024]
    float* __restrict__ lp)                  // [16][65536] logit partials
{
  __shared__ __align__(16) unsigned short Asm[128 * BK];  // 16 KiB, XOR-swizzled
  __shared__ __align__(16) unsigned short Bsm[128 * BK];

  const int mc = *mcount;
  const int mtiles = (mc + 127) >> 7;              // active A-panels
  const int T = mtiles * 8;
  if ((int)blockIdx.x >= T) return;
  const int swz = ((int)blockIdx.x % 8) * mtiles + (int)blockIdx.x / 8;
  const int nt8 = swz & 7;
  const int mt = swz >> 3;
  const int m0 = mt * 128, n0 = nt8 * 128;

  const int t = threadIdx.x;
  const int lane = t & 63;
  const int w = t >> 6;
  const int wm = w >> 1, wn = w & 1;     // 2x2 waves of 64x64
  const int g = lane >> 4, c16 = lane & 15;

  f32x4 acc[4][4];
#pragma unroll
  for (int a = 0; a < 4; ++a)
#pragma unroll
    for (int b = 0; b < 4; ++b) acc[a][b] = {0.f, 0.f, 0.f, 0.f};

  const unsigned short* gA[4];
  const unsigned short* gB[4];
#pragma unroll
  for (int r = 0; r < 4; ++r) {
    int item = r * 256 + t;
    int row = item >> 3;
    int sub = (item & 7) ^ (row & 7);  // inverse swizzle on SOURCE
    gA[r] = Abf + (size_t)(m0 + row) * K_DIM + sub * 8;
    gB[r] = B   + (size_t)(n0 + row) * K_DIM + sub * 8;
  }

  for (int kt = 0; kt < NT; ++kt) {
#pragma unroll
    for (int r = 0; r < 4; ++r) {
      __builtin_amdgcn_global_load_lds(
          (const __attribute__((address_space(1))) void*)gA[r],
          (__attribute__((address_space(3))) void*)&Asm[(r * 256 + t) * 8],
          16, 0, 0);
      gA[r] += BK;
      __builtin_amdgcn_global_load_lds(
          (const __attribute__((address_space(1))) void*)gB[r],
          (__attribute__((address_space(3))) void*)&Bsm[(r * 256 + t) * 8],
          16, 0, 0);
      gB[r] += BK;
    }
    __syncthreads();
#pragma unroll
    for (int ks = 0; ks < 2; ++ks) {
      const int sub = ks * 4 + g;
      short8 af[4], bfr[4];
#pragma unroll
      for (int a = 0; a < 4; ++a) {
        int row = wm * 64 + a * 16 + c16;
        af[a] = *(const short8*)&Asm[row * 64 + ((sub ^ (row & 7)) * 8)];
      }
#pragma unroll
      for (int b = 0; b < 4; ++b) {
        int row = wn * 64 + b * 16 + c16;
        bfr[b] = *(const short8*)&Bsm[row * 64 + ((sub ^ (row & 7)) * 8)];
      }
#pragma unroll
      for (int a = 0; a < 4; ++a)
#pragma unroll
        for (int b = 0; b < 4; ++b)
          acc[a][b] = __builtin_amdgcn_mfma_f32_16x16x32_bf16(
              af[a], bfr[b], acc[a][b], 0, 0, 0);
    }
    __syncthreads();
  }

  float* slab = lp + (size_t)(nt8 * 2 + wn) * M_TOT;
#pragma unroll
  for (int a = 0; a < 4; ++a) {
    int brow[4];
#pragma unroll
    for (int j = 0; j < 4; ++j) {
      int cj = m0 + wm * 64 + a * 16 + g * 4 + j;
      brow[j] = (cj < mc) ? (ridx[cj] & 31) : 0;
    }
    float psum[4] = {0.f, 0.f, 0.f, 0.f};
#pragma unroll
    for (int b = 0; b < 4; ++b) {
      const int col = n0 + wn * 64 + b * 16 + c16;
      const float wo = wout[col];
#pragma unroll
      for (int j = 0; j < 4; ++j) {
        float v = acc[a][b][j] + pdec[brow[j] * N_DIM + col];
        psum[j] = fmaf(tanh_fast(v), wo, psum[j]);
      }
    }
#pragma unroll
    for (int j = 0; j < 4; ++j) {
      float p = psum[j];
      p += __shfl_xor(p, 1);
      p += __shfl_xor(p, 2);
      p += __shfl_xor(p, 4);
      p += __shfl_xor(p, 8);
      if (c16 == 0)
        slab[m0 + wm * 64 + a * 16 + g * 4 + j] = p;
    }
  }
}

// ---- coalesced slab sum: lsum[j] = sum_k lp[k][j], j < mcount ----
__global__ void k_sumslab(const float* __restrict__ lp,
                          const int* __restrict__ mcount,
                          float* __restrict__ lsum) {
  const int mc = *mcount;
  for (int i = blockIdx.x * 256 + threadIdx.x; i < mc; i += gridDim.x * 256) {
    float s = 0.f;
#pragma unroll
    for (int k = 0; k < NSLAB; ++k) s += lp[(size_t)k * M_TOT + i];
    lsum[i] = s;
  }
}

// ---- fallback f32-A GEMM over ALL rows ----
__global__ __launch_bounds__(256) void k_gemm_f32(
    const float* __restrict__ A,
    const unsigned short* __restrict__ B,
    const float* __restrict__ pdec,
    const float* __restrict__ wout,
    float* __restrict__ lp)
{
  __shared__ __align__(16) unsigned short Asm[128 * BK];
  __shared__ __align__(16) unsigned short Bsm[128 * BK];
  const int bid = blockIdx.x;
  const int nt8 = bid & 7;
  const int mt = bid >> 3;
  const int m0 = mt * 128, n0 = nt8 * 128;
  const int t = threadIdx.x;
  const int lane = t & 63;
  const int w = t >> 6;
  const int wm = w >> 1, wn = w & 1;
  const int g = lane >> 4, c16 = lane & 15;

  f32x4 acc[4][4];
#pragma unroll
  for (int a = 0; a < 4; ++a)
#pragma unroll
    for (int b = 0; b < 4; ++b) acc[a][b] = {0.f, 0.f, 0.f, 0.f};

  for (int kt = 0; kt < NT; ++kt) {
    const int k0 = kt * BK;
#pragma unroll
    for (int i = 0; i < 4; ++i) {
      int item = i * 256 + t;
      int row = item >> 3;
      int sub = item & 7;
      const float* src = A + (size_t)(m0 + row) * K_DIM + k0 + sub * 8;
      f32x4 v0 = *(const f32x4*)src;
      f32x4 v1 = *(const f32x4*)(src + 4);
      uint4 o;
      o.x = pack_bf16x2(v0.x, v0.y);
      o.y = pack_bf16x2(v0.z, v0.w);
      o.z = pack_bf16x2(v1.x, v1.y);
      o.w = pack_bf16x2(v1.z, v1.w);
      int chunk = sub ^ (row & 7);
      *(uint4*)&Asm[row * 64 + chunk * 8] = o;
    }
#pragma unroll
    for (int j = 0; j < 4; ++j) {
      int chunkid = w * 4 + j;
      int item = chunkid * 64 + lane;
      int row = item >> 3;
      int sub = (item & 7) ^ (row & 7);
      const unsigned short* gp = B + (size_t)(n0 + row) * K_DIM + k0 + sub * 8;
      __builtin_amdgcn_global_load_lds(
          (const __attribute__((address_space(1))) void*)gp,
          (__attribute__((address_space(3))) void*)&Bsm[chunkid * 512],
          16, 0, 0);
    }
    __syncthreads();
#pragma unroll
    for (int ks = 0; ks < 2; ++ks) {
      const int sub = ks * 4 + g;
      short8 af[4], bfr[4];
#pragma unroll
      for (int a = 0; a < 4; ++a) {
        int row = wm * 64 + a * 16 + c16;
        af[a] = *(const short8*)&Asm[row * 64 + ((sub ^ (row & 7)) * 8)];
      }
#pragma unroll
      for (int b = 0; b < 4; ++b) {
        int row = wn * 64 + b * 16 + c16;
        bfr[b] = *(const short8*)&Bsm[row * 64 + ((sub ^ (row & 7)) * 8)];
      }
#pragma unroll
      for (int a = 0; a < 4; ++a)
#pragma unroll
        for (int b = 0; b < 4; ++b)
          acc[a][b] = __builtin_amdgcn_mfma_f32_16x16x32_bf16(
              af[a], bfr[b], acc[a][b], 0, 0, 0);
    }
    __syncthreads();
  }
  float* slab = lp + (size_t)(nt8 * 2 + wn) * M_TOT;
#pragma unroll
  for (int a = 0; a < 4; ++a) {
    float psum[4] = {0.f, 0.f, 0.f, 0.f};
#pragma unroll
    for (int b = 0; b < 4; ++b) {
      const int col = n0 + wn * 64 + b * 16 + c16;
      const float wo = wout[col];
#pragma unroll
      for (int j = 0; j < 4; ++j) {
        const int rl = wm * 64 + a * 16 + g * 4 + j;
        const int bidx = rl & 31;
        float v = acc[a][b][j] + pdec[bidx * N_DIM + col];
        psum[j] = fmaf(tanh_fast(v), wo, psum[j]);
      }
    }
#pragma unroll
    for (int j = 0; j < 4; ++j) {
      float p = psum[j];
      p += __shfl_xor(p, 1);
      p += __shfl_xor(p, 2);
      p += __shfl_xor(p, 4);
      p += __shfl_xor(p, 8);
      if (c16 == 0)
        slab[m0 + wm * 64 + a * 16 + g * 4 + j] = p;
    }
  }
}

// ---- masked softmax. GATHER: one read from lsum[pos[i]]; else 16 slabs. ----
template <bool GATHER>
__global__ void k_softmax(const float* __restrict__ lsrc,
                          const int* __restrict__ pos,
                          const void* __restrict__ maskp,
                          float* __restrict__ weights) {
  const int b = blockIdx.x;
  const int t = threadIdx.x;
  const int lane = t & 63, wid = t >> 6;
  __shared__ float red[8];
  __shared__ int mf[2];

  int mode = 0;
  if (!GATHER) mode = mask_mode_detect(maskp, t, mf);

  float v[8];
  float mx = -3.0e38f;
#pragma unroll
  for (int i = 0; i < 8; ++i) {
    int idx = (t + i * 256) * BATCH + b;
    float l;
    if (GATHER) {
      int p = pos[idx];
      l = (p >= 0) ? lsrc[p] : -2.0e9f;
    } else {
      l = 0.f;
#pragma unroll
      for (int k = 0; k < NSLAB; ++k) l += lsrc[(size_t)k * M_TOT + idx];
      l = mask_read(maskp, mode, idx) ? l : -2.0e9f;
    }
    v[i] = l;
    mx = fmaxf(mx, l);
  }
#pragma unroll
  for (int off = 1; off < 64; off <<= 1) mx = fmaxf(mx, __shfl_xor(mx, off));
  if (lane == 0) red[wid] = mx;
  __syncthreads();
  mx = fmaxf(fmaxf(red[0], red[1]), fmaxf(red[2], red[3]));

  float sum = 0.f;
#pragma unroll
  for (int i = 0; i < 8; ++i) {
    float e = __expf(v[i] - mx);
    v[i] = e;
    sum += e;
  }
#pragma unroll
  for (int off = 1; off < 64; off <<= 1) sum += __shfl_xor(sum, off);
  if (lane == 0) red[4 + wid] = sum;
  __syncthreads();
  sum = red[4] + red[5] + red[6] + red[7];
  float inv = 1.0f / sum;
#pragma unroll
  for (int i = 0; i < 8; ++i)
    weights[(t + i * 256) * BATCH + b] = v[i] * inv;
}

// ---- owner-block response: plain stores, no memset, no atomics ----
// grid = 32 b x 8 col-chunks; block 256 = 2 s-halves x 128 cols.
__global__ __launch_bounds__(256) void k_response3(
    const float* __restrict__ enc,
    const unsigned short* __restrict__ cmp,
    const int* __restrict__ pos,
    const float* __restrict__ weights,
    float* __restrict__ out) {
  const int b = blockIdx.x & 31;
  const int q = blockIdx.x >> 5;           // 0..7
  const int t = threadIdx.x;
  const int cl = t & 127;                  // col within chunk
  const int sh = t >> 7;                   // s-half 0/1
  const int col = q * 128 + cl;
  __shared__ float partial[256];

  float acc = 0.f;
  const int s0 = sh * (N_ENC / 2);
  for (int s = s0; s < s0 + N_ENC / 2; ++s) {
    const int idx = s * BATCH + b;
    const float wv = weights[idx];
    if (wv != 0.f) {                       // uniform branch per s
      const int p = pos[idx];
      float x = (p >= 0) ? bf2f(cmp[(size_t)p * K_DIM + col])
                         : enc[(size_t)idx * K_DIM + col];
      acc = fmaf(wv, x, acc);
    }
  }
  partial[t] = acc;
  __syncthreads();
  if (t < 128) out[b * K_DIM + col] = partial[t] + partial[t + 128];
}

// ---- f32 atomic response (fallback path; launcher zeroes out first) ----
__global__ void k_response(const float* __restrict__ enc,
                           const float* __restrict__ weights,
                           float* __restrict__ out) {
  const int b = blockIdx.x & 31;
  const int ch = blockIdx.x >> 5;
  const int e = threadIdx.x * 4;
  float a0 = 0.f, a1 = 0.f, a2 = 0.f, a3 = 0.f;
  const int s0 = ch * (N_ENC / 16);
  for (int s = s0; s < s0 + N_ENC / 16; ++s) {
    float wv = weights[s * BATCH + b];
    f32x4 x = *(const f32x4*)(enc + ((size_t)s * BATCH + b) * K_DIM + e);
    a0 = fmaf(wv, x.x, a0);
    a1 = fmaf(wv, x.y, a1);
    a2 = fmaf(wv, x.z, a2);
    a3 = fmaf(wv, x.w, a3);
  }
  atomicAdd(&out[b * K_DIM + e + 0], a0);
  atomicAdd(&out[b * K_DIM + e + 1], a1);
  atomicAdd(&out[b * K_DIM + e + 2], a2);
  atomicAdd(&out[b * K_DIM + e + 3], a3);
}

extern "C" void kernel_launch(void* const* d_in, const int* in_sizes, int n_in,
                              void* d_out, int out_size, void* d_ws, size_t ws_size,
                              hipStream_t stream) {
  const float* enc   = (const float*)d_in[0];
  const void*  mask  = d_in[1];
  const float* dec   = (const float*)d_in[2];
  const float* w_enc = (const float*)d_in[3];
  const float* w_dec = (const float*)d_in[4];
  const float* w_out = (const float*)d_in[5];

  float* out_resp = (float*)d_out;                 // [32*1024]
  float* out_w    = out_resp + BATCH * K_DIM;      // [2048*32]

  const size_t cmp_bytes = (size_t)M_TOT * K_DIM * 2;          // 128 MiB
  const size_t tail = 2 * 1024 * 1024 + 128 * 1024 +
                      (size_t)NSLAB * M_TOT * 4 +              // lp 4 MiB
                      (size_t)M_TOT * 4 * 3 + 8192;            // pos+ridx+lsum+bcnt
  const bool pre = ws_size >= cmp_bytes + tail;

  char* wsB = (char*)d_ws;
  unsigned short* cmp = (unsigned short*)wsB;
  size_t off = pre ? cmp_bytes : 0;
  unsigned short* w_enc_bf = (unsigned short*)(wsB + off);     off += 2 * 1024 * 1024;
  float* pdec = (float*)(wsB + off);                           off += 128 * 1024;
  float* lp   = (float*)(wsB + off);                           off += (size_t)NSLAB * M_TOT * 4;
  int* pos    = (int*)(wsB + off);                             off += (size_t)M_TOT * 4;
  int* ridx   = (int*)(wsB + off);                             off += (size_t)M_TOT * 4;
  float* lsum = (float*)(wsB + off);                           off += (size_t)M_TOT * 4;
  int* bcnt   = (int*)(wsB + off);                             off += 1024 * 4;
  int* mcount = (int*)(wsB + off);

  k_convert_bf16<<<512, 256, 0, stream>>>(w_enc, w_enc_bf, N_DIM * K_DIM / 8);
  k_proj_dec<<<N_DIM / 8, 256, 0, stream>>>(dec, w_dec, pdec);

  if (pre) {
    k_count<<<M_TOT / 256, 256, 0, stream>>>(mask, bcnt);
    k_fill<<<M_TOT / 256, 256, 0, stream>>>(mask, bcnt, pos, ridx, mcount);
    k_gather_cvt<<<2048, 256, 0, stream>>>(enc, ridx, mcount, cmp);
    k_gemm128<<<(M_TOT / 128) * (N_DIM / 128), 256, 0, stream>>>(
        cmp, w_enc_bf, ridx, mcount, pdec, w_out, lp);
    k_sumslab<<<256, 256, 0, stream>>>(lp, mcount, lsum);
    k_softmax<true><<<BATCH, 256, 0, stream>>>(lsum, pos, mask, out_w);
    k_response3<<<BATCH * 8, 256, 0, stream>>>(enc, cmp, pos, out_w, out_resp);
  } else {
    hipMemsetAsync(out_resp, 0, (size_t)BATCH * K_DIM * sizeof(float), stream);
    k_gemm_f32<<<(M_TOT / 128) * (N_DIM / 128), 256, 0, stream>>>(
        enc, w_enc_bf, pdec, w_out, lp);
    k_softmax<false><<<BATCH, 256, 0, stream>>>(lp, pos, mask, out_w);
    k_response<<<BATCH * 16, 256, 0, stream>>>(enc, out_w, out_resp);
  }
}

// Round 17
// 227.272 us; speedup vs baseline: 2.5672x; 2.5672x over previous
//
#include <hip/hip_runtime.h>
#include <hip/hip_bf16.h>
#include <stdint.h>

#define N_ENC 2048
#define BATCH 32
#define M_TOT (N_ENC * BATCH)   // 65536 rows (s*32+b)
#define K_DIM 1024
#define N_DIM 1024
#define BK 64
#define NT (K_DIM / BK)          // 16 K-tiles
#define NSLAB 16                 // nt8*2 + wn (race-free logit partials)

typedef __attribute__((ext_vector_type(4))) float f32x4;
typedef __attribute__((ext_vector_type(8))) short short8;

__device__ __forceinline__ unsigned int pack_bf16x2(float lo, float hi) {
  unsigned int a = __float_as_uint(lo);
  unsigned int b = __float_as_uint(hi);
  a = (a + 0x7fffu + ((a >> 16) & 1u)) >> 16;          // RNE to bf16, low half
  b = (b + 0x7fffu + ((b >> 16) & 1u)) & 0xffff0000u;  // RNE to bf16, high half
  return a | b;
}

__device__ __forceinline__ float bf2f(unsigned short u) {
  return __uint_as_float((unsigned int)u << 16);
}

__device__ __forceinline__ float tanh_fast(float x) {
  float e = __expf(2.0f * x);
  return 1.0f - 2.0f / (e + 1.0f);
}

__device__ __forceinline__ int mask_mode_detect(const void* maskp, int t,
                                                int* mf) {
  if (t < 2) mf[t] = 0;
  __syncthreads();
  unsigned w0 = ((const unsigned*)maskp)[t & 255];
  if (t < 256) {
    if (w0 == 0x3f800000u) mf[1] = 1;
    else if (w0 > 1u) mf[0] = 1;
  }
  __syncthreads();
  return mf[1] ? 2 : (mf[0] ? 1 : 0);
}

__device__ __forceinline__ int mask_read(const void* maskp, int mode, int idx) {
  if (mode == 0) return ((const int*)maskp)[idx] != 0;
  if (mode == 1) return ((const unsigned char*)maskp)[idx] != 0;
  return ((const float*)maskp)[idx] != 0.f;
}

// ---- zero out_resp (avoids rocclr fill inside the graph) ----
__global__ void k_zero(float* __restrict__ p, int n4) {
  int i = blockIdx.x * 256 + threadIdx.x;
  if (i < n4) ((f32x4*)p)[i] = f32x4{0.f, 0.f, 0.f, 0.f};
}

// ---- phase 1: per-block (256 rows) mask counts ----
__global__ __launch_bounds__(256) void k_count(const void* __restrict__ maskp,
                                               int* __restrict__ bcnt) {
  const int t = threadIdx.x, lane = t & 63, wv = t >> 6;
  __shared__ int mf[2];
  __shared__ int ws_[4];
  const int mode = mask_mode_detect(maskp, t, mf);
  const int idx = blockIdx.x * 256 + t;
  int mk = mask_read(maskp, mode, idx);
  unsigned long long bal = __ballot(mk);
  if (lane == 0) ws_[wv] = __popcll(bal);
  __syncthreads();
  if (t == 0) bcnt[blockIdx.x] = ws_[0] + ws_[1] + ws_[2] + ws_[3];
}

// ---- phase 2: pos/ridx fill via block-prefix + in-block ballot compaction ----
__global__ __launch_bounds__(256) void k_fill(const void* __restrict__ maskp,
                                              const int* __restrict__ bcnt,
                                              int* __restrict__ pos,
                                              int* __restrict__ ridx,
                                              int* __restrict__ mcount) {
  const int t = threadIdx.x, lane = t & 63, wv = t >> 6;
  __shared__ int mf[2];
  __shared__ int sc[256];
  __shared__ int wtot[4];
  __shared__ int wcnt[4];
  const int mode = mask_mode_detect(maskp, t, mf);

  int x = bcnt[t];
#pragma unroll
  for (int d = 1; d < 64; d <<= 1) {
    int y = __shfl_up(x, d);
    if (lane >= d) x += y;
  }
  if (lane == 63) wtot[wv] = x;
  __syncthreads();
  int add = 0;
  for (int i = 0; i < wv; ++i) add += wtot[i];
  sc[t] = x + add;
  __syncthreads();
  const int blockoff = blockIdx.x ? sc[blockIdx.x - 1] : 0;
  if (blockIdx.x == 0 && t == 0) *mcount = sc[255];

  const int idx = blockIdx.x * 256 + t;
  int mk = mask_read(maskp, mode, idx);
  unsigned long long bal = __ballot(mk);
  int lpfx = __popcll(bal & ((1ULL << lane) - 1ULL));
  if (lane == 0) wcnt[wv] = __popcll(bal);
  __syncthreads();
  int wb = 0;
  for (int i = 0; i < wv; ++i) wb += wcnt[i];
  int off = blockoff + wb + lpfx;
  if (mk) { pos[idx] = off; ridx[off] = idx; }
  else pos[idx] = -1;
}

// ---- gather + f32->bf16: cmp[j] = bf16(enc[ridx[j]]), j < mcount ----
__global__ void k_gather_cvt(const float* __restrict__ enc,
                             const int* __restrict__ ridx,
                             const int* __restrict__ mcount,
                             unsigned short* __restrict__ cmp) {
  const int mc = *mcount;
  const int e = threadIdx.x * 4;
  for (int j = blockIdx.x; j < mc; j += gridDim.x) {
    const int row = ridx[j];
    f32x4 v = *(const f32x4*)(enc + (size_t)row * K_DIM + e);
    uint2 o;
    o.x = pack_bf16x2(v.x, v.y);
    o.y = pack_bf16x2(v.z, v.w);
    *(uint2*)(cmp + (size_t)j * K_DIM + e) = o;
  }
}

// ---- w_enc f32 -> bf16 ----
__global__ void k_convert_bf16(const float* __restrict__ src,
                               unsigned short* __restrict__ dst, int n8) {
  for (int i = blockIdx.x * 256 + threadIdx.x; i < n8; i += gridDim.x * 256) {
    const float* p = src + (size_t)i * 8;
    f32x4 v0 = *(const f32x4*)p;
    f32x4 v1 = *(const f32x4*)(p + 4);
    uint4 o;
    o.x = pack_bf16x2(v0.x, v0.y);
    o.y = pack_bf16x2(v0.z, v0.w);
    o.z = pack_bf16x2(v1.x, v1.y);
    o.w = pack_bf16x2(v1.z, v1.w);
    *(uint4*)(dst + (size_t)i * 8) = o;
  }
}

// ---- proj_dec[b][h] = sum_d dec[b][d] * w_dec[h][d] ----
__global__ void k_proj_dec(const float* __restrict__ dec,
                           const float* __restrict__ w_dec,
                           float* __restrict__ proj) {
  int t = threadIdx.x;
  int hh = t & 7, b = t >> 3;
  int h = blockIdx.x * 8 + hh;
  const float* wr = w_dec + (size_t)h * K_DIM;
  const float* dr = dec + (size_t)b * K_DIM;
  float acc = 0.f;
  for (int d = 0; d < K_DIM; d += 4) {
    f32x4 wv = *(const f32x4*)(wr + d);
    f32x4 dv = *(const f32x4*)(dr + d);
    acc = fmaf(wv.x, dv.x, acc);
    acc = fmaf(wv.y, dv.y, acc);
    acc = fmaf(wv.z, dv.z, acc);
    acc = fmaf(wv.w, dv.w, acc);
  }
  proj[b * N_DIM + h] = acc;
}

// ---- R9 GEMM on compacted rows; compaction-aware XCD swizzle ----
__global__ __launch_bounds__(256, 3) void k_gemm128(
    const unsigned short* __restrict__ Abf,  // cmp bf16
    const unsigned short* __restrict__ B,    // w_enc bf16 [1024][1024]
    const int* __restrict__ ridx,
    const int* __restrict__ mcount,
    const float* __restrict__ pdec,          // [32][1024]
    const float* __restrict__ wout,          // [1024]
    float* __restrict__ lp)                  // [16][65536] logit partials
{
  __shared__ __align__(16) unsigned short Asm[128 * BK];  // 16 KiB, XOR-swizzled
  __shared__ __align__(16) unsigned short Bsm[128 * BK];

  const int mc = *mcount;
  const int mtiles = (mc + 127) >> 7;              // active A-panels
  const int T = mtiles * 8;
  if ((int)blockIdx.x >= T) return;
  const int swz = ((int)blockIdx.x % 8) * mtiles + (int)blockIdx.x / 8;
  const int nt8 = swz & 7;
  const int mt = swz >> 3;
  const int m0 = mt * 128, n0 = nt8 * 128;

  const int t = threadIdx.x;
  const int lane = t & 63;
  const int w = t >> 6;
  const int wm = w >> 1, wn = w & 1;     // 2x2 waves of 64x64
  const int g = lane >> 4, c16 = lane & 15;

  f32x4 acc[4][4];
#pragma unroll
  for (int a = 0; a < 4; ++a)
#pragma unroll
    for (int b = 0; b < 4; ++b) acc[a][b] = {0.f, 0.f, 0.f, 0.f};

  const unsigned short* gA[4];
  const unsigned short* gB[4];
#pragma unroll
  for (int r = 0; r < 4; ++r) {
    int item = r * 256 + t;
    int row = item >> 3;
    int sub = (item & 7) ^ (row & 7);  // inverse swizzle on SOURCE
    gA[r] = Abf + (size_t)(m0 + row) * K_DIM + sub * 8;
    gB[r] = B   + (size_t)(n0 + row) * K_DIM + sub * 8;
  }

  for (int kt = 0; kt < NT; ++kt) {
#pragma unroll
    for (int r = 0; r < 4; ++r) {
      __builtin_amdgcn_global_load_lds(
          (const __attribute__((address_space(1))) void*)gA[r],
          (__attribute__((address_space(3))) void*)&Asm[(r * 256 + t) * 8],
          16, 0, 0);
      gA[r] += BK;
      __builtin_amdgcn_global_load_lds(
          (const __attribute__((address_space(1))) void*)gB[r],
          (__attribute__((address_space(3))) void*)&Bsm[(r * 256 + t) * 8],
          16, 0, 0);
      gB[r] += BK;
    }
    __syncthreads();
#pragma unroll
    for (int ks = 0; ks < 2; ++ks) {
      const int sub = ks * 4 + g;
      short8 af[4], bfr[4];
#pragma unroll
      for (int a = 0; a < 4; ++a) {
        int row = wm * 64 + a * 16 + c16;
        af[a] = *(const short8*)&Asm[row * 64 + ((sub ^ (row & 7)) * 8)];
      }
#pragma unroll
      for (int b = 0; b < 4; ++b) {
        int row = wn * 64 + b * 16 + c16;
        bfr[b] = *(const short8*)&Bsm[row * 64 + ((sub ^ (row & 7)) * 8)];
      }
#pragma unroll
      for (int a = 0; a < 4; ++a)
#pragma unroll
        for (int b = 0; b < 4; ++b)
          acc[a][b] = __builtin_amdgcn_mfma_f32_16x16x32_bf16(
              af[a], bfr[b], acc[a][b], 0, 0, 0);
    }
    __syncthreads();
  }

  float* slab = lp + (size_t)(nt8 * 2 + wn) * M_TOT;
#pragma unroll
  for (int a = 0; a < 4; ++a) {
    int brow[4];
#pragma unroll
    for (int j = 0; j < 4; ++j) {
      int cj = m0 + wm * 64 + a * 16 + g * 4 + j;
      brow[j] = (cj < mc) ? (ridx[cj] & 31) : 0;
    }
    float psum[4] = {0.f, 0.f, 0.f, 0.f};
#pragma unroll
    for (int b = 0; b < 4; ++b) {
      const int col = n0 + wn * 64 + b * 16 + c16;
      const float wo = wout[col];
#pragma unroll
      for (int j = 0; j < 4; ++j) {
        float v = acc[a][b][j] + pdec[brow[j] * N_DIM + col];
        psum[j] = fmaf(tanh_fast(v), wo, psum[j]);
      }
    }
#pragma unroll
    for (int j = 0; j < 4; ++j) {
      float p = psum[j];
      p += __shfl_xor(p, 1);
      p += __shfl_xor(p, 2);
      p += __shfl_xor(p, 4);
      p += __shfl_xor(p, 8);
      if (c16 == 0)
        slab[m0 + wm * 64 + a * 16 + g * 4 + j] = p;
    }
  }
}

// ---- coalesced slab sum: lsum[j] = sum_k lp[k][j], j < mcount ----
__global__ void k_sumslab(const float* __restrict__ lp,
                          const int* __restrict__ mcount,
                          float* __restrict__ lsum) {
  const int mc = *mcount;
  for (int i = blockIdx.x * 256 + threadIdx.x; i < mc; i += gridDim.x * 256) {
    float s = 0.f;
#pragma unroll
    for (int k = 0; k < NSLAB; ++k) s += lp[(size_t)k * M_TOT + i];
    lsum[i] = s;
  }
}

// ---- fallback f32-A GEMM over ALL rows ----
__global__ __launch_bounds__(256) void k_gemm_f32(
    const float* __restrict__ A,
    const unsigned short* __restrict__ B,
    const float* __restrict__ pdec,
    const float* __restrict__ wout,
    float* __restrict__ lp)
{
  __shared__ __align__(16) unsigned short Asm[128 * BK];
  __shared__ __align__(16) unsigned short Bsm[128 * BK];
  const int bid = blockIdx.x;
  const int nt8 = bid & 7;
  const int mt = bid >> 3;
  const int m0 = mt * 128, n0 = nt8 * 128;
  const int t = threadIdx.x;
  const int lane = t & 63;
  const int w = t >> 6;
  const int wm = w >> 1, wn = w & 1;
  const int g = lane >> 4, c16 = lane & 15;

  f32x4 acc[4][4];
#pragma unroll
  for (int a = 0; a < 4; ++a)
#pragma unroll
    for (int b = 0; b < 4; ++b) acc[a][b] = {0.f, 0.f, 0.f, 0.f};

  for (int kt = 0; kt < NT; ++kt) {
    const int k0 = kt * BK;
#pragma unroll
    for (int i = 0; i < 4; ++i) {
      int item = i * 256 + t;
      int row = item >> 3;
      int sub = item & 7;
      const float* src = A + (size_t)(m0 + row) * K_DIM + k0 + sub * 8;
      f32x4 v0 = *(const f32x4*)src;
      f32x4 v1 = *(const f32x4*)(src + 4);
      uint4 o;
      o.x = pack_bf16x2(v0.x, v0.y);
      o.y = pack_bf16x2(v0.z, v0.w);
      o.z = pack_bf16x2(v1.x, v1.y);
      o.w = pack_bf16x2(v1.z, v1.w);
      int chunk = sub ^ (row & 7);
      *(uint4*)&Asm[row * 64 + chunk * 8] = o;
    }
#pragma unroll
    for (int j = 0; j < 4; ++j) {
      int chunkid = w * 4 + j;
      int item = chunkid * 64 + lane;
      int row = item >> 3;
      int sub = (item & 7) ^ (row & 7);
      const unsigned short* gp = B + (size_t)(n0 + row) * K_DIM + k0 + sub * 8;
      __builtin_amdgcn_global_load_lds(
          (const __attribute__((address_space(1))) void*)gp,
          (__attribute__((address_space(3))) void*)&Bsm[chunkid * 512],
          16, 0, 0);
    }
    __syncthreads();
#pragma unroll
    for (int ks = 0; ks < 2; ++ks) {
      const int sub = ks * 4 + g;
      short8 af[4], bfr[4];
#pragma unroll
      for (int a = 0; a < 4; ++a) {
        int row = wm * 64 + a * 16 + c16;
        af[a] = *(const short8*)&Asm[row * 64 + ((sub ^ (row & 7)) * 8)];
      }
#pragma unroll
      for (int b = 0; b < 4; ++b) {
        int row = wn * 64 + b * 16 + c16;
        bfr[b] = *(const short8*)&Bsm[row * 64 + ((sub ^ (row & 7)) * 8)];
      }
#pragma unroll
      for (int a = 0; a < 4; ++a)
#pragma unroll
        for (int b = 0; b < 4; ++b)
          acc[a][b] = __builtin_amdgcn_mfma_f32_16x16x32_bf16(
              af[a], bfr[b], acc[a][b], 0, 0, 0);
    }
    __syncthreads();
  }
  float* slab = lp + (size_t)(nt8 * 2 + wn) * M_TOT;
#pragma unroll
  for (int a = 0; a < 4; ++a) {
    float psum[4] = {0.f, 0.f, 0.f, 0.f};
#pragma unroll
    for (int b = 0; b < 4; ++b) {
      const int col = n0 + wn * 64 + b * 16 + c16;
      const float wo = wout[col];
#pragma unroll
      for (int j = 0; j < 4; ++j) {
        const int rl = wm * 64 + a * 16 + g * 4 + j;
        const int bidx = rl & 31;
        float v = acc[a][b][j] + pdec[bidx * N_DIM + col];
        psum[j] = fmaf(tanh_fast(v), wo, psum[j]);
      }
    }
#pragma unroll
    for (int j = 0; j < 4; ++j) {
      float p = psum[j];
      p += __shfl_xor(p, 1);
      p += __shfl_xor(p, 2);
      p += __shfl_xor(p, 4);
      p += __shfl_xor(p, 8);
      if (c16 == 0)
        slab[m0 + wm * 64 + a * 16 + g * 4 + j] = p;
    }
  }
}

// ---- masked softmax. GATHER: one read from lsum[pos[i]]; else 16 slabs. ----
template <bool GATHER>
__global__ void k_softmax(const float* __restrict__ lsrc,
                          const int* __restrict__ pos,
                          const void* __restrict__ maskp,
                          float* __restrict__ weights) {
  const int b = blockIdx.x;
  const int t = threadIdx.x;
  const int lane = t & 63, wid = t >> 6;
  __shared__ float red[8];
  __shared__ int mf[2];

  int mode = 0;
  if (!GATHER) mode = mask_mode_detect(maskp, t, mf);

  float v[8];
  float mx = -3.0e38f;
#pragma unroll
  for (int i = 0; i < 8; ++i) {
    int idx = (t + i * 256) * BATCH + b;
    float l;
    if (GATHER) {
      int p = pos[idx];
      l = (p >= 0) ? lsrc[p] : -2.0e9f;
    } else {
      l = 0.f;
#pragma unroll
      for (int k = 0; k < NSLAB; ++k) l += lsrc[(size_t)k * M_TOT + idx];
      l = mask_read(maskp, mode, idx) ? l : -2.0e9f;
    }
    v[i] = l;
    mx = fmaxf(mx, l);
  }
#pragma unroll
  for (int off = 1; off < 64; off <<= 1) mx = fmaxf(mx, __shfl_xor(mx, off));
  if (lane == 0) red[wid] = mx;
  __syncthreads();
  mx = fmaxf(fmaxf(red[0], red[1]), fmaxf(red[2], red[3]));

  float sum = 0.f;
#pragma unroll
  for (int i = 0; i < 8; ++i) {
    float e = __expf(v[i] - mx);
    v[i] = e;
    sum += e;
  }
#pragma unroll
  for (int off = 1; off < 64; off <<= 1) sum += __shfl_xor(sum, off);
  if (lane == 0) red[4 + wid] = sum;
  __syncthreads();
  sum = red[4] + red[5] + red[6] + red[7];
  float inv = 1.0f / sum;
#pragma unroll
  for (int i = 0; i < 8; ++i)
    weights[(t + i * 256) * BATCH + b] = v[i] * inv;
}

// ---- response (R15 structure, more TLP): 32 b x 32 s-chunks, atomics ----
__global__ void k_response2(const float* __restrict__ enc,
                            const unsigned short* __restrict__ cmp,
                            const int* __restrict__ pos,
                            const float* __restrict__ weights,
                            float* __restrict__ out) {
  const int b = blockIdx.x & 31;
  const int ch = blockIdx.x >> 5;          // 32 s-chunks of 64
  const int e = threadIdx.x * 4;
  float a0 = 0.f, a1 = 0.f, a2 = 0.f, a3 = 0.f;
  const int s0 = ch * (N_ENC / 32);
  for (int s = s0; s < s0 + N_ENC / 32; ++s) {
    const int idx = s * BATCH + b;
    float wv = weights[idx];
    if (wv != 0.f) {
      int p = pos[idx];
      if (p >= 0) {
        ushort4 x = *(const ushort4*)(cmp + (size_t)p * K_DIM + e);
        a0 = fmaf(wv, bf2f(x.x), a0);
        a1 = fmaf(wv, bf2f(x.y), a1);
        a2 = fmaf(wv, bf2f(x.z), a2);
        a3 = fmaf(wv, bf2f(x.w), a3);
      } else {
        f32x4 x = *(const f32x4*)(enc + (size_t)idx * K_DIM + e);
        a0 = fmaf(wv, x.x, a0);
        a1 = fmaf(wv, x.y, a1);
        a2 = fmaf(wv, x.z, a2);
        a3 = fmaf(wv, x.w, a3);
      }
    }
  }
  atomicAdd(&out[b * K_DIM + e + 0], a0);
  atomicAdd(&out[b * K_DIM + e + 1], a1);
  atomicAdd(&out[b * K_DIM + e + 2], a2);
  atomicAdd(&out[b * K_DIM + e + 3], a3);
}

// ---- f32 atomic response (fallback path) ----
__global__ void k_response(const float* __restrict__ enc,
                           const float* __restrict__ weights,
                           float* __restrict__ out) {
  const int b = blockIdx.x & 31;
  const int ch = blockIdx.x >> 5;
  const int e = threadIdx.x * 4;
  float a0 = 0.f, a1 = 0.f, a2 = 0.f, a3 = 0.f;
  const int s0 = ch * (N_ENC / 16);
  for (int s = s0; s < s0 + N_ENC / 16; ++s) {
    float wv = weights[s * BATCH + b];
    f32x4 x = *(const f32x4*)(enc + ((size_t)s * BATCH + b) * K_DIM + e);
    a0 = fmaf(wv, x.x, a0);
    a1 = fmaf(wv, x.y, a1);
    a2 = fmaf(wv, x.z, a2);
    a3 = fmaf(wv, x.w, a3);
  }
  atomicAdd(&out[b * K_DIM + e + 0], a0);
  atomicAdd(&out[b * K_DIM + e + 1], a1);
  atomicAdd(&out[b * K_DIM + e + 2], a2);
  atomicAdd(&out[b * K_DIM + e + 3], a3);
}

extern "C" void kernel_launch(void* const* d_in, const int* in_sizes, int n_in,
                              void* d_out, int out_size, void* d_ws, size_t ws_size,
                              hipStream_t stream) {
  const float* enc   = (const float*)d_in[0];
  const void*  mask  = d_in[1];
  const float* dec   = (const float*)d_in[2];
  const float* w_enc = (const float*)d_in[3];
  const float* w_dec = (const float*)d_in[4];
  const float* w_out = (const float*)d_in[5];

  float* out_resp = (float*)d_out;                 // [32*1024]
  float* out_w    = out_resp + BATCH * K_DIM;      // [2048*32]

  const size_t cmp_bytes = (size_t)M_TOT * K_DIM * 2;          // 128 MiB
  const size_t tail = 2 * 1024 * 1024 + 128 * 1024 +
                      (size_t)NSLAB * M_TOT * 4 +
                      (size_t)M_TOT * 4 * 3 + 8192;
  const bool pre = ws_size >= cmp_bytes + tail;

  char* wsB = (char*)d_ws;
  unsigned short* cmp = (unsigned short*)wsB;
  size_t off = pre ? cmp_bytes : 0;
  unsigned short* w_enc_bf = (unsigned short*)(wsB + off);     off += 2 * 1024 * 1024;
  float* pdec = (float*)(wsB + off);                           off += 128 * 1024;
  float* lp   = (float*)(wsB + off);                           off += (size_t)NSLAB * M_TOT * 4;
  int* pos    = (int*)(wsB + off);                             off += (size_t)M_TOT * 4;
  int* ridx   = (int*)(wsB + off);                             off += (size_t)M_TOT * 4;
  float* lsum = (float*)(wsB + off);                           off += (size_t)M_TOT * 4;
  int* bcnt   = (int*)(wsB + off);                             off += 1024 * 4;
  int* mcount = (int*)(wsB + off);

  k_zero<<<(BATCH * K_DIM / 4 + 255) / 256, 256, 0, stream>>>(
      out_resp, BATCH * K_DIM / 4);
  k_convert_bf16<<<512, 256, 0, stream>>>(w_enc, w_enc_bf, N_DIM * K_DIM / 8);
  k_proj_dec<<<N_DIM / 8, 256, 0, stream>>>(dec, w_dec, pdec);

  if (pre) {
    k_count<<<M_TOT / 256, 256, 0, stream>>>(mask, bcnt);
    k_fill<<<M_TOT / 256, 256, 0, stream>>>(mask, bcnt, pos, ridx, mcount);
    k_gather_cvt<<<2048, 256, 0, stream>>>(enc, ridx, mcount, cmp);
    k_gemm128<<<(M_TOT / 128) * (N_DIM / 128), 256, 0, stream>>>(
        cmp, w_enc_bf, ridx, mcount, pdec, w_out, lp);
    k_sumslab<<<256, 256, 0, stream>>>(lp, mcount, lsum);
    k_softmax<true><<<BATCH, 256, 0, stream>>>(lsum, pos, mask, out_w);
    k_response2<<<BATCH * 32, 256, 0, stream>>>(enc, cmp, pos, out_w, out_resp);
  } else {
    k_gemm_f32<<<(M_TOT / 128) * (N_DIM / 128), 256, 0, stream>>>(
        enc, w_enc_bf, pdec, w_out, lp);
    k_softmax<false><<<BATCH, 256, 0, stream>>>(lp, pos, mask, out_w);
    k_response<<<BATCH * 16, 256, 0, stream>>>(enc, out_w, out_resp);
  }
}

// Round 18
// 220.786 us; speedup vs baseline: 2.6426x; 1.0294x over previous
//
#include <hip/hip_runtime.h>
#include <hip/hip_bf16.h>
#include <stdint.h>

#define N_ENC 2048
#define BATCH 32
#define M_TOT (N_ENC * BATCH)   // 65536 rows (s*32+b)
#define K_DIM 1024
#define N_DIM 1024
#define BK 64
#define NT (K_DIM / BK)          // 16 K-tiles
#define NSLAB 16                 // nt8*2 + wn (race-free logit partials)

typedef __attribute__((ext_vector_type(4))) float f32x4;
typedef __attribute__((ext_vector_type(8))) short short8;

__device__ __forceinline__ unsigned int pack_bf16x2(float lo, float hi) {
  unsigned int a = __float_as_uint(lo);
  unsigned int b = __float_as_uint(hi);
  a = (a + 0x7fffu + ((a >> 16) & 1u)) >> 16;          // RNE to bf16, low half
  b = (b + 0x7fffu + ((b >> 16) & 1u)) & 0xffff0000u;  // RNE to bf16, high half
  return a | b;
}

__device__ __forceinline__ float bf2f(unsigned short u) {
  return __uint_as_float((unsigned int)u << 16);
}

__device__ __forceinline__ float tanh_fast(float x) {
  float e = __expf(2.0f * x);
  return 1.0f - 2.0f / (e + 1.0f);
}

__device__ __forceinline__ int mask_mode_detect(const void* maskp, int t,
                                                int* mf) {
  if (t < 2) mf[t] = 0;
  __syncthreads();
  unsigned w0 = ((const unsigned*)maskp)[t & 255];
  if (t < 256) {
    if (w0 == 0x3f800000u) mf[1] = 1;
    else if (w0 > 1u) mf[0] = 1;
  }
  __syncthreads();
  return mf[1] ? 2 : (mf[0] ? 1 : 0);
}

__device__ __forceinline__ int mask_read(const void* maskp, int mode, int idx) {
  if (mode == 0) return ((const int*)maskp)[idx] != 0;
  if (mode == 1) return ((const unsigned char*)maskp)[idx] != 0;
  return ((const float*)maskp)[idx] != 0.f;
}

// ---- fused prep: [0,512) convert w_enc; [512,640) proj_dec; [640,672) zero ----
__global__ __launch_bounds__(256) void k_prep(
    const float* __restrict__ w_enc, unsigned short* __restrict__ w_enc_bf,
    const float* __restrict__ dec, const float* __restrict__ w_dec,
    float* __restrict__ pdec, float* __restrict__ out_resp) {
  const int blk = blockIdx.x;
  const int t = threadIdx.x;
  if (blk < 512) {
    // convert w_enc: 131072 8-elem items, one per thread
    int i = blk * 256 + t;
    const float* p = w_enc + (size_t)i * 8;
    f32x4 v0 = *(const f32x4*)p;
    f32x4 v1 = *(const f32x4*)(p + 4);
    uint4 o;
    o.x = pack_bf16x2(v0.x, v0.y);
    o.y = pack_bf16x2(v0.z, v0.w);
    o.z = pack_bf16x2(v1.x, v1.y);
    o.w = pack_bf16x2(v1.z, v1.w);
    *(uint4*)(w_enc_bf + (size_t)i * 8) = o;
  } else if (blk < 640) {
    // proj_dec: 8 h x 32 b per block
    int hh = t & 7, b = t >> 3;
    int h = (blk - 512) * 8 + hh;
    const float* wr = w_dec + (size_t)h * K_DIM;
    const float* dr = dec + (size_t)b * K_DIM;
    float acc = 0.f;
    for (int d = 0; d < K_DIM; d += 4) {
      f32x4 wv = *(const f32x4*)(wr + d);
      f32x4 dv = *(const f32x4*)(dr + d);
      acc = fmaf(wv.x, dv.x, acc);
      acc = fmaf(wv.y, dv.y, acc);
      acc = fmaf(wv.z, dv.z, acc);
      acc = fmaf(wv.w, dv.w, acc);
    }
    pdec[b * N_DIM + h] = acc;
  } else {
    // zero out_resp: 32 blocks x 256 x f32x4 = 32768 floats
    int i = (blk - 640) * 256 + t;
    ((f32x4*)out_resp)[i] = f32x4{0.f, 0.f, 0.f, 0.f};
  }
}

// ---- phase 1: per-block (256 rows) mask counts ----
__global__ __launch_bounds__(256) void k_count(const void* __restrict__ maskp,
                                               int* __restrict__ bcnt) {
  const int t = threadIdx.x, lane = t & 63, wv = t >> 6;
  __shared__ int mf[2];
  __shared__ int ws_[4];
  const int mode = mask_mode_detect(maskp, t, mf);
  const int idx = blockIdx.x * 256 + t;
  int mk = mask_read(maskp, mode, idx);
  unsigned long long bal = __ballot(mk);
  if (lane == 0) ws_[wv] = __popcll(bal);
  __syncthreads();
  if (t == 0) bcnt[blockIdx.x] = ws_[0] + ws_[1] + ws_[2] + ws_[3];
}

// ---- phase 2: pos/ridx fill via block-prefix + in-block ballot compaction ----
__global__ __launch_bounds__(256) void k_fill(const void* __restrict__ maskp,
                                              const int* __restrict__ bcnt,
                                              int* __restrict__ pos,
                                              int* __restrict__ ridx,
                                              int* __restrict__ mcount) {
  const int t = threadIdx.x, lane = t & 63, wv = t >> 6;
  __shared__ int mf[2];
  __shared__ int sc[256];
  __shared__ int wtot[4];
  __shared__ int wcnt[4];
  const int mode = mask_mode_detect(maskp, t, mf);

  int x = bcnt[t];
#pragma unroll
  for (int d = 1; d < 64; d <<= 1) {
    int y = __shfl_up(x, d);
    if (lane >= d) x += y;
  }
  if (lane == 63) wtot[wv] = x;
  __syncthreads();
  int add = 0;
  for (int i = 0; i < wv; ++i) add += wtot[i];
  sc[t] = x + add;
  __syncthreads();
  const int blockoff = blockIdx.x ? sc[blockIdx.x - 1] : 0;
  if (blockIdx.x == 0 && t == 0) *mcount = sc[255];

  const int idx = blockIdx.x * 256 + t;
  int mk = mask_read(maskp, mode, idx);
  unsigned long long bal = __ballot(mk);
  int lpfx = __popcll(bal & ((1ULL << lane) - 1ULL));
  if (lane == 0) wcnt[wv] = __popcll(bal);
  __syncthreads();
  int wb = 0;
  for (int i = 0; i < wv; ++i) wb += wcnt[i];
  int off = blockoff + wb + lpfx;
  if (mk) { pos[idx] = off; ridx[off] = idx; }
  else pos[idx] = -1;
}

// ---- gather + f32->bf16: cmp[j] = bf16(enc[ridx[j]]); 16B stores ----
__global__ void k_gather_cvt(const float* __restrict__ enc,
                             const int* __restrict__ ridx,
                             const int* __restrict__ mcount,
                             unsigned short* __restrict__ cmp) {
  const int mc = *mcount;
  const int t = threadIdx.x;
  const int half = t >> 7;                 // 2 rows per block-iter
  const int e = (t & 127) * 8;             // 8 f32 per thread
  for (int j0 = blockIdx.x * 2; j0 < mc; j0 += gridDim.x * 2) {
    const int j = j0 + half;
    if (j < mc) {
      const int row = ridx[j];
      const float* p = enc + (size_t)row * K_DIM + e;
      f32x4 v0 = *(const f32x4*)p;
      f32x4 v1 = *(const f32x4*)(p + 4);
      uint4 o;
      o.x = pack_bf16x2(v0.x, v0.y);
      o.y = pack_bf16x2(v0.z, v0.w);
      o.z = pack_bf16x2(v1.x, v1.y);
      o.w = pack_bf16x2(v1.z, v1.w);
      *(uint4*)(cmp + (size_t)j * K_DIM + e) = o;
    }
  }
}

// ---- R9 GEMM on compacted rows; compaction-aware XCD swizzle ----
__global__ __launch_bounds__(256, 3) void k_gemm128(
    const unsigned short* __restrict__ Abf,  // cmp bf16
    const unsigned short* __restrict__ B,    // w_enc bf16 [1024][1024]
    const int* __restrict__ ridx,
    const int* __restrict__ mcount,
    const float* __restrict__ pdec,          // [32][1024]
    const float* __restrict__ wout,          // [1024]
    float* __restrict__ lp)                  // [16][65536] logit partials
{
  __shared__ __align__(16) unsigned short Asm[128 * BK];  // 16 KiB, XOR-swizzled
  __shared__ __align__(16) unsigned short Bsm[128 * BK];

  const int mc = *mcount;
  const int mtiles = (mc + 127) >> 7;              // active A-panels
  const int T = mtiles * 8;
  if ((int)blockIdx.x >= T) return;
  const int swz = ((int)blockIdx.x % 8) * mtiles + (int)blockIdx.x / 8;
  const int nt8 = swz & 7;
  const int mt = swz >> 3;
  const int m0 = mt * 128, n0 = nt8 * 128;

  const int t = threadIdx.x;
  const int lane = t & 63;
  const int w = t >> 6;
  const int wm = w >> 1, wn = w & 1;     // 2x2 waves of 64x64
  const int g = lane >> 4, c16 = lane & 15;

  f32x4 acc[4][4];
#pragma unroll
  for (int a = 0; a < 4; ++a)
#pragma unroll
    for (int b = 0; b < 4; ++b) acc[a][b] = {0.f, 0.f, 0.f, 0.f};

  const unsigned short* gA[4];
  const unsigned short* gB[4];
#pragma unroll
  for (int r = 0; r < 4; ++r) {
    int item = r * 256 + t;
    int row = item >> 3;
    int sub = (item & 7) ^ (row & 7);  // inverse swizzle on SOURCE
    gA[r] = Abf + (size_t)(m0 + row) * K_DIM + sub * 8;
    gB[r] = B   + (size_t)(n0 + row) * K_DIM + sub * 8;
  }

  for (int kt = 0; kt < NT; ++kt) {
#pragma unroll
    for (int r = 0; r < 4; ++r) {
      __builtin_amdgcn_global_load_lds(
          (const __attribute__((address_space(1))) void*)gA[r],
          (__attribute__((address_space(3))) void*)&Asm[(r * 256 + t) * 8],
          16, 0, 0);
      gA[r] += BK;
      __builtin_amdgcn_global_load_lds(
          (const __attribute__((address_space(1))) void*)gB[r],
          (__attribute__((address_space(3))) void*)&Bsm[(r * 256 + t) * 8],
          16, 0, 0);
      gB[r] += BK;
    }
    __syncthreads();
#pragma unroll
    for (int ks = 0; ks < 2; ++ks) {
      const int sub = ks * 4 + g;
      short8 af[4], bfr[4];
#pragma unroll
      for (int a = 0; a < 4; ++a) {
        int row = wm * 64 + a * 16 + c16;
        af[a] = *(const short8*)&Asm[row * 64 + ((sub ^ (row & 7)) * 8)];
      }
#pragma unroll
      for (int b = 0; b < 4; ++b) {
        int row = wn * 64 + b * 16 + c16;
        bfr[b] = *(const short8*)&Bsm[row * 64 + ((sub ^ (row & 7)) * 8)];
      }
#pragma unroll
      for (int a = 0; a < 4; ++a)
#pragma unroll
        for (int b = 0; b < 4; ++b)
          acc[a][b] = __builtin_amdgcn_mfma_f32_16x16x32_bf16(
              af[a], bfr[b], acc[a][b], 0, 0, 0);
    }
    __syncthreads();
  }

  float* slab = lp + (size_t)(nt8 * 2 + wn) * M_TOT;
#pragma unroll
  for (int a = 0; a < 4; ++a) {
    int brow[4];
#pragma unroll
    for (int j = 0; j < 4; ++j) {
      int cj = m0 + wm * 64 + a * 16 + g * 4 + j;
      brow[j] = (cj < mc) ? (ridx[cj] & 31) : 0;
    }
    float psum[4] = {0.f, 0.f, 0.f, 0.f};
#pragma unroll
    for (int b = 0; b < 4; ++b) {
      const int col = n0 + wn * 64 + b * 16 + c16;
      const float wo = wout[col];
#pragma unroll
      for (int j = 0; j < 4; ++j) {
        float v = acc[a][b][j] + pdec[brow[j] * N_DIM + col];
        psum[j] = fmaf(tanh_fast(v), wo, psum[j]);
      }
    }
#pragma unroll
    for (int j = 0; j < 4; ++j) {
      float p = psum[j];
      p += __shfl_xor(p, 1);
      p += __shfl_xor(p, 2);
      p += __shfl_xor(p, 4);
      p += __shfl_xor(p, 8);
      if (c16 == 0)
        slab[m0 + wm * 64 + a * 16 + g * 4 + j] = p;
    }
  }
}

// ---- coalesced slab sum: lsum[j] = sum_k lp[k][j], j < mcount ----
__global__ void k_sumslab(const float* __restrict__ lp,
                          const int* __restrict__ mcount,
                          float* __restrict__ lsum) {
  const int mc = *mcount;
  for (int i = blockIdx.x * 256 + threadIdx.x; i < mc; i += gridDim.x * 256) {
    float s = 0.f;
#pragma unroll
    for (int k = 0; k < NSLAB; ++k) s += lp[(size_t)k * M_TOT + i];
    lsum[i] = s;
  }
}

// ---- fallback f32-A GEMM over ALL rows ----
__global__ __launch_bounds__(256) void k_gemm_f32(
    const float* __restrict__ A,
    const unsigned short* __restrict__ B,
    const float* __restrict__ pdec,
    const float* __restrict__ wout,
    float* __restrict__ lp)
{
  __shared__ __align__(16) unsigned short Asm[128 * BK];
  __shared__ __align__(16) unsigned short Bsm[128 * BK];
  const int bid = blockIdx.x;
  const int nt8 = bid & 7;
  const int mt = bid >> 3;
  const int m0 = mt * 128, n0 = nt8 * 128;
  const int t = threadIdx.x;
  const int lane = t & 63;
  const int w = t >> 6;
  const int wm = w >> 1, wn = w & 1;
  const int g = lane >> 4, c16 = lane & 15;

  f32x4 acc[4][4];
#pragma unroll
  for (int a = 0; a < 4; ++a)
#pragma unroll
    for (int b = 0; b < 4; ++b) acc[a][b] = {0.f, 0.f, 0.f, 0.f};

  for (int kt = 0; kt < NT; ++kt) {
    const int k0 = kt * BK;
#pragma unroll
    for (int i = 0; i < 4; ++i) {
      int item = i * 256 + t;
      int row = item >> 3;
      int sub = item & 7;
      const float* src = A + (size_t)(m0 + row) * K_DIM + k0 + sub * 8;
      f32x4 v0 = *(const f32x4*)src;
      f32x4 v1 = *(const f32x4*)(src + 4);
      uint4 o;
      o.x = pack_bf16x2(v0.x, v0.y);
      o.y = pack_bf16x2(v0.z, v0.w);
      o.z = pack_bf16x2(v1.x, v1.y);
      o.w = pack_bf16x2(v1.z, v1.w);
      int chunk = sub ^ (row & 7);
      *(uint4*)&Asm[row * 64 + chunk * 8] = o;
    }
#pragma unroll
    for (int j = 0; j < 4; ++j) {
      int chunkid = w * 4 + j;
      int item = chunkid * 64 + lane;
      int row = item >> 3;
      int sub = (item & 7) ^ (row & 7);
      const unsigned short* gp = B + (size_t)(n0 + row) * K_DIM + k0 + sub * 8;
      __builtin_amdgcn_global_load_lds(
          (const __attribute__((address_space(1))) void*)gp,
          (__attribute__((address_space(3))) void*)&Bsm[chunkid * 512],
          16, 0, 0);
    }
    __syncthreads();
#pragma unroll
    for (int ks = 0; ks < 2; ++ks) {
      const int sub = ks * 4 + g;
      short8 af[4], bfr[4];
#pragma unroll
      for (int a = 0; a < 4; ++a) {
        int row = wm * 64 + a * 16 + c16;
        af[a] = *(const short8*)&Asm[row * 64 + ((sub ^ (row & 7)) * 8)];
      }
#pragma unroll
      for (int b = 0; b < 4; ++b) {
        int row = wn * 64 + b * 16 + c16;
        bfr[b] = *(const short8*)&Bsm[row * 64 + ((sub ^ (row & 7)) * 8)];
      }
#pragma unroll
      for (int a = 0; a < 4; ++a)
#pragma unroll
        for (int b = 0; b < 4; ++b)
          acc[a][b] = __builtin_amdgcn_mfma_f32_16x16x32_bf16(
              af[a], bfr[b], acc[a][b], 0, 0, 0);
    }
    __syncthreads();
  }
  float* slab = lp + (size_t)(nt8 * 2 + wn) * M_TOT;
#pragma unroll
  for (int a = 0; a < 4; ++a) {
    float psum[4] = {0.f, 0.f, 0.f, 0.f};
#pragma unroll
    for (int b = 0; b < 4; ++b) {
      const int col = n0 + wn * 64 + b * 16 + c16;
      const float wo = wout[col];
#pragma unroll
      for (int j = 0; j < 4; ++j) {
        const int rl = wm * 64 + a * 16 + g * 4 + j;
        const int bidx = rl & 31;
        float v = acc[a][b][j] + pdec[bidx * N_DIM + col];
        psum[j] = fmaf(tanh_fast(v), wo, psum[j]);
      }
    }
#pragma unroll
    for (int j = 0; j < 4; ++j) {
      float p = psum[j];
      p += __shfl_xor(p, 1);
      p += __shfl_xor(p, 2);
      p += __shfl_xor(p, 4);
      p += __shfl_xor(p, 8);
      if (c16 == 0)
        slab[m0 + wm * 64 + a * 16 + g * 4 + j] = p;
    }
  }
}

// ---- masked softmax. GATHER: one read from lsum[pos[i]]; else 16 slabs. ----
template <bool GATHER>
__global__ void k_softmax(const float* __restrict__ lsrc,
                          const int* __restrict__ pos,
                          const void* __restrict__ maskp,
                          float* __restrict__ weights) {
  const int b = blockIdx.x;
  const int t = threadIdx.x;
  const int lane = t & 63, wid = t >> 6;
  __shared__ float red[8];
  __shared__ int mf[2];

  int mode = 0;
  if (!GATHER) mode = mask_mode_detect(maskp, t, mf);

  float v[8];
  float mx = -3.0e38f;
#pragma unroll
  for (int i = 0; i < 8; ++i) {
    int idx = (t + i * 256) * BATCH + b;
    float l;
    if (GATHER) {
      int p = pos[idx];
      l = (p >= 0) ? lsrc[p] : -2.0e9f;
    } else {
      l = 0.f;
#pragma unroll
      for (int k = 0; k < NSLAB; ++k) l += lsrc[(size_t)k * M_TOT + idx];
      l = mask_read(maskp, mode, idx) ? l : -2.0e9f;
    }
    v[i] = l;
    mx = fmaxf(mx, l);
  }
#pragma unroll
  for (int off = 1; off < 64; off <<= 1) mx = fmaxf(mx, __shfl_xor(mx, off));
  if (lane == 0) red[wid] = mx;
  __syncthreads();
  mx = fmaxf(fmaxf(red[0], red[1]), fmaxf(red[2], red[3]));

  float sum = 0.f;
#pragma unroll
  for (int i = 0; i < 8; ++i) {
    float e = __expf(v[i] - mx);
    v[i] = e;
    sum += e;
  }
#pragma unroll
  for (int off = 1; off < 64; off <<= 1) sum += __shfl_xor(sum, off);
  if (lane == 0) red[4 + wid] = sum;
  __syncthreads();
  sum = red[4] + red[5] + red[6] + red[7];
  float inv = 1.0f / sum;
#pragma unroll
  for (int i = 0; i < 8; ++i)
    weights[(t + i * 256) * BATCH + b] = v[i] * inv;
}

// ---- response: 32 b x 32 s-chunks, coalesced reads, atomics ----
__global__ void k_response2(const float* __restrict__ enc,
                            const unsigned short* __restrict__ cmp,
                            const int* __restrict__ pos,
                            const float* __restrict__ weights,
                            float* __restrict__ out) {
  const int b = blockIdx.x & 31;
  const int ch = blockIdx.x >> 5;          // 32 s-chunks of 64
  const int e = threadIdx.x * 4;
  float a0 = 0.f, a1 = 0.f, a2 = 0.f, a3 = 0.f;
  const int s0 = ch * (N_ENC / 32);
  for (int s = s0; s < s0 + N_ENC / 32; ++s) {
    const int idx = s * BATCH + b;
    float wv = weights[idx];
    if (wv != 0.f) {
      int p = pos[idx];
      if (p >= 0) {
        ushort4 x = *(const ushort4*)(cmp + (size_t)p * K_DIM + e);
        a0 = fmaf(wv, bf2f(x.x), a0);
        a1 = fmaf(wv, bf2f(x.y), a1);
        a2 = fmaf(wv, bf2f(x.z), a2);
        a3 = fmaf(wv, bf2f(x.w), a3);
      } else {
        f32x4 x = *(const f32x4*)(enc + (size_t)idx * K_DIM + e);
        a0 = fmaf(wv, x.x, a0);
        a1 = fmaf(wv, x.y, a1);
        a2 = fmaf(wv, x.z, a2);
        a3 = fmaf(wv, x.w, a3);
      }
    }
  }
  atomicAdd(&out[b * K_DIM + e + 0], a0);
  atomicAdd(&out[b * K_DIM + e + 1], a1);
  atomicAdd(&out[b * K_DIM + e + 2], a2);
  atomicAdd(&out[b * K_DIM + e + 3], a3);
}

// ---- f32 atomic response (fallback path) ----
__global__ void k_response(const float* __restrict__ enc,
                           const float* __restrict__ weights,
                           float* __restrict__ out) {
  const int b = blockIdx.x & 31;
  const int ch = blockIdx.x >> 5;
  const int e = threadIdx.x * 4;
  float a0 = 0.f, a1 = 0.f, a2 = 0.f, a3 = 0.f;
  const int s0 = ch * (N_ENC / 16);
  for (int s = s0; s < s0 + N_ENC / 16; ++s) {
    float wv = weights[s * BATCH + b];
    f32x4 x = *(const f32x4*)(enc + ((size_t)s * BATCH + b) * K_DIM + e);
    a0 = fmaf(wv, x.x, a0);
    a1 = fmaf(wv, x.y, a1);
    a2 = fmaf(wv, x.z, a2);
    a3 = fmaf(wv, x.w, a3);
  }
  atomicAdd(&out[b * K_DIM + e + 0], a0);
  atomicAdd(&out[b * K_DIM + e + 1], a1);
  atomicAdd(&out[b * K_DIM + e + 2], a2);
  atomicAdd(&out[b * K_DIM + e + 3], a3);
}

extern "C" void kernel_launch(void* const* d_in, const int* in_sizes, int n_in,
                              void* d_out, int out_size, void* d_ws, size_t ws_size,
                              hipStream_t stream) {
  const float* enc   = (const float*)d_in[0];
  const void*  mask  = d_in[1];
  const float* dec   = (const float*)d_in[2];
  const float* w_enc = (const float*)d_in[3];
  const float* w_dec = (const float*)d_in[4];
  const float* w_out = (const float*)d_in[5];

  float* out_resp = (float*)d_out;                 // [32*1024]
  float* out_w    = out_resp + BATCH * K_DIM;      // [2048*32]

  const size_t cmp_bytes = (size_t)M_TOT * K_DIM * 2;          // 128 MiB
  const size_t tail = 2 * 1024 * 1024 + 128 * 1024 +
                      (size_t)NSLAB * M_TOT * 4 +
                      (size_t)M_TOT * 4 * 3 + 8192;
  const bool pre = ws_size >= cmp_bytes + tail;

  char* wsB = (char*)d_ws;
  unsigned short* cmp = (unsigned short*)wsB;
  size_t off = pre ? cmp_bytes : 0;
  unsigned short* w_enc_bf = (unsigned short*)(wsB + off);     off += 2 * 1024 * 1024;
  float* pdec = (float*)(wsB + off);                           off += 128 * 1024;
  float* lp   = (float*)(wsB + off);                           off += (size_t)NSLAB * M_TOT * 4;
  int* pos    = (int*)(wsB + off);                             off += (size_t)M_TOT * 4;
  int* ridx   = (int*)(wsB + off);                             off += (size_t)M_TOT * 4;
  float* lsum = (float*)(wsB + off);                           off += (size_t)M_TOT * 4;
  int* bcnt   = (int*)(wsB + off);                             off += 1024 * 4;
  int* mcount = (int*)(wsB + off);

  k_prep<<<672, 256, 0, stream>>>(w_enc, w_enc_bf, dec, w_dec, pdec, out_resp);

  if (pre) {
    k_count<<<M_TOT / 256, 256, 0, stream>>>(mask, bcnt);
    k_fill<<<M_TOT / 256, 256, 0, stream>>>(mask, bcnt, pos, ridx, mcount);
    k_gather_cvt<<<2048, 256, 0, stream>>>(enc, ridx, mcount, cmp);
    k_gemm128<<<(M_TOT / 128) * (N_DIM / 128), 256, 0, stream>>>(
        cmp, w_enc_bf, ridx, mcount, pdec, w_out, lp);
    k_sumslab<<<256, 256, 0, stream>>>(lp, mcount, lsum);
    k_softmax<true><<<BATCH, 256, 0, stream>>>(lsum, pos, mask, out_w);
    k_response2<<<BATCH * 32, 256, 0, stream>>>(enc, cmp, pos, out_w, out_resp);
  } else {
    k_gemm_f32<<<(M_TOT / 128) * (N_DIM / 128), 256, 0, stream>>>(
        enc, w_enc_bf, pdec, w_out, lp);
    k_softmax<false><<<BATCH, 256, 0, stream>>>(lp, pos, mask, out_w);
    k_response<<<BATCH * 16, 256, 0, stream>>>(enc, out_w, out_resp);
  }
}